// Round 3
// baseline (165.814 us; speedup 1.0000x reference)
//
#include <hip/hip_runtime.h>
#include <hip/hip_cooperative_groups.h>

namespace cg = cooperative_groups;

typedef float f32x2 __attribute__((ext_vector_type(2)));
typedef float f32x4 __attribute__((ext_vector_type(4)));
typedef _Float16 h16x2 __attribute__((ext_vector_type(2)));
typedef _Float16 h16x4 __attribute__((ext_vector_type(4)));
typedef _Float16 h16x8 __attribute__((ext_vector_type(8)));

#define LL 512

#if __has_builtin(__builtin_amdgcn_exp2f)
#define EXP2F __builtin_amdgcn_exp2f
#else
#define EXP2F exp2f
#endif
#define LOG2E 1.44269504088896340736f

__device__ __forceinline__ float quad_swap1(float x) {
    return __int_as_float(__builtin_amdgcn_mov_dpp(__float_as_int(x), 0xB1, 0xF, 0xF, true));
}
__device__ __forceinline__ float quad_swap2(float x) {
    return __int_as_float(__builtin_amdgcn_mov_dpp(__float_as_int(x), 0x4E, 0xF, 0xF, true));
}

__device__ __forceinline__ float fdot2f(h16x2 a, h16x2 b, float c) {
#if __has_builtin(__builtin_amdgcn_fdot2)
    return __builtin_amdgcn_fdot2(a, b, c, false);
#else
    return fmaf((float)a.x, (float)b.x, fmaf((float)a.y, (float)b.y, c));
#endif
}

// ---------------------------------------------------------------------------
// R14: single cooperative kernel = gemm phase + grid.sync + attn phase.
// Removes one dispatch + the inter-kernel drain/launch gap (~10 us theory).
//
// Phase 1 (gemm): each block runs 3 of the original 768 128-thread tiles as
// 3 concurrent sub-blocks (t < 384; waves 0-5). Per-CU configuration is
// IDENTICAL to the old 3-blocks/CU layout (same 4x4 micro, 1 B/FLOP LDS
// ratio, same double-buffer) -> gemm stays at its 11.6 us LDS-BW floor.
// Consecutive tile ids per block share the same W panel -> L2 hits.
//
// Phase 2 (attn): unchanged R13 body (8 q/block half-wave dup, depth-2
// pipeline). LDS union: gemm 79.9 KB vs accbuf 139.3 KB -> 139,264 B,
// 1 block/CU, grid 256 = #CUs (co-residency for grid.sync).
// Bit-identical op order in both phases -> absmax unchanged.
// ---------------------------------------------------------------------------
union Smem {
    struct { float As[3][2][32][36]; float Bs[3][2][32][68]; } g;  // 79,872 B
    float accbuf[16][64][34];                                      // 139,264 B
};

__global__ __launch_bounds__(1024, 4) void fused_all(
    const float* __restrict__ X, const float* __restrict__ Wq,
    const float* __restrict__ Wk, const float* __restrict__ Wv,
    const float* __restrict__ w_mlp, const float* __restrict__ b_mlp,
    _Float16* __restrict__ Qh, _Float16* __restrict__ Kh, float* __restrict__ Vt,
    float* __restrict__ out)
{
    __shared__ Smem sm;
    const int bid = blockIdx.x;              // 0..255
    const int t = threadIdx.x;               // 0..1023

    // ================= phase 1: QKV GEMM (3 sub-blocks of 128 thr) =========
    {
        const int sb = t >> 7;               // 0..7
        const bool act = (sb < 3);
        const int lt = t & 127;
        const int T = bid * 3 + sb;          // tile id 0..767 when act
        const int mat = T >> 8;              // 0..2 when act
        const int n0 = ((T >> 6) & 3) * 64;
        const int m0 = (T & 63) * 32;
        const float* W = (mat == 0) ? Wq : (mat == 1 ? Wk : Wv);

        const int tx = lt & 15;              // n micro
        const int ty = lt >> 4;              // m micro (0..7)

        int am[2], ak4[2];
#pragma unroll
        for (int r = 0; r < 2; ++r) { int idx = lt + 128 * r; am[r] = idx >> 3; ak4[r] = idx & 7; }
        int bn[4], bk4[4]; size_t brow[4];
#pragma unroll
        for (int r = 0; r < 4; ++r) {
            int idx = lt + 128 * r; bn[r] = idx >> 3; bk4[r] = idx & 7;
            int rowc = n0 + bn[r];
            brow[r] = (mat == 2) ? (size_t)(((rowc & 31) << 3) | (rowc >> 5)) : (size_t)rowc;
        }

        f32x4 arg[2], brg[4];
        auto load_tile = [&](int kc) {
#pragma unroll
            for (int r = 0; r < 2; ++r)
                arg[r] = *(const f32x4*)(X + (size_t)(m0 + am[r]) * 256 + kc + ak4[r] * 4);
#pragma unroll
            for (int r = 0; r < 4; ++r)
                brg[r] = *(const f32x4*)(W + brow[r] * 256 + kc + bk4[r] * 4);
        };
        auto store_tile = [&](int buf) {
#pragma unroll
            for (int r = 0; r < 2; ++r)
#pragma unroll
                for (int j = 0; j < 4; ++j) sm.g.As[sb][buf][ak4[r] * 4 + j][am[r]] = arg[r][j];
#pragma unroll
            for (int r = 0; r < 4; ++r)
#pragma unroll
                for (int j = 0; j < 4; ++j) sm.g.Bs[sb][buf][bk4[r] * 4 + j][bn[r]] = brg[r][j];
        };

        if (act) { load_tile(0); store_tile(0); }
        __syncthreads();

        f32x2 c[4][2];
#pragma unroll
        for (int i = 0; i < 4; ++i) { c[i][0] = (f32x2){0.f, 0.f}; c[i][1] = (f32x2){0.f, 0.f}; }

        for (int it = 0; it < 8; ++it) {
            const int buf = it & 1;
            if (act) {
                if (it < 7) load_tile((it + 1) * 32);
#pragma unroll
                for (int kk = 0; kk < 32; ++kk) {
                    const f32x4 a4 = *(const f32x4*)&sm.g.As[sb][buf][kk][ty * 4];
                    const f32x4 b4 = *(const f32x4*)&sm.g.Bs[sb][buf][kk][tx * 4];
                    const f32x2 bl = __builtin_shufflevector(b4, b4, 0, 1);
                    const f32x2 bh = __builtin_shufflevector(b4, b4, 2, 3);
#pragma unroll
                    for (int i = 0; i < 4; ++i) {
                        const f32x2 ai = {a4[i], a4[i]};
                        c[i][0] += ai * bl;
                        c[i][1] += ai * bh;
                    }
                }
            }
            if (it < 7) {
                __syncthreads();
                if (act) store_tile(buf ^ 1);
                __syncthreads();
            }
        }

        if (act) {
            const int colb = n0 + tx * 4;
            if (mat == 2) {
#pragma unroll
                for (int i = 0; i < 4; ++i) {
                    f32x4 v = {c[i][0].x, c[i][0].y, c[i][1].x, c[i][1].y};
                    *(f32x4*)(Vt + (size_t)(m0 + ty * 4 + i) * 256 + colb) = v;
                }
            } else {
                _Float16* Hb = (mat == 0) ? Qh : Kh;
#pragma unroll
                for (int i = 0; i < 4; ++i) {
                    h16x4 hv = {(_Float16)c[i][0].x, (_Float16)c[i][0].y,
                                (_Float16)c[i][1].x, (_Float16)c[i][1].y};
                    *(h16x4*)(Hb + (size_t)(m0 + ty * 4 + i) * 256 + colb) = hv;
                }
            }
        }
    }

    cg::this_grid().sync();

    // ================= phase 2: fused grouped-MLP attention =================
    {
        const int b = bid & 3;
        const int q0 = (bid >> 2) * 8;       // 64 q-tiles of 8 per batch

        const int p = t >> 6;                // 0..15  k-phase (= wave id)
        const int lane64 = t & 63;
        const int half = (t >> 5) & 1;       // q-half: 0 -> q0..+3, 1 -> q0+4..+7
        const int lane32 = t & 31;
        const int dh = t & 3;
        const int g = lane32 >> 2;

        const int doff = g * 32 + dh * 8;
        const float bias4 = b_mlp[0] * (LOG2E * 0.25f);
        const bool odd = (dh & 1) != 0;
        const bool hi  = (dh & 2) != 0;

        h16x2 w2[4];
        {
            f32x4 wa = *(const f32x4*)(w_mlp + dh * 8);
            f32x4 wb = *(const f32x4*)(w_mlp + dh * 8 + 4);
            wa *= LOG2E; wb *= LOG2E;
            w2[0] = (h16x2){(_Float16)wa.x, (_Float16)wa.y};
            w2[1] = (h16x2){(_Float16)wa.z, (_Float16)wa.w};
            w2[2] = (h16x2){(_Float16)wb.x, (_Float16)wb.y};
            w2[3] = (h16x2){(_Float16)wb.z, (_Float16)wb.w};
        }

        h16x2 qr2[4][4];
#pragma unroll
        for (int q = 0; q < 4; ++q) {
            const h16x8 qv = *(const h16x8*)(Qh + ((size_t)(b * LL) + q0 + half * 4 + q) * 256 + doff);
            qr2[q][0] = __builtin_shufflevector(qv, qv, 0, 1);
            qr2[q][1] = __builtin_shufflevector(qv, qv, 2, 3);
            qr2[q][2] = __builtin_shufflevector(qv, qv, 4, 5);
            qr2[q][3] = __builtin_shufflevector(qv, qv, 6, 7);
        }

        f32x2 acc2[4][4];                    // slot s <-> local q = dh ^ s
#pragma unroll
        for (int s = 0; s < 4; ++s)
#pragma unroll
            for (int j = 0; j < 4; ++j) acc2[s][j] = (f32x2){0.f, 0.f};
        float lown = 0.f;                    // l for local q == dh

        const _Float16* kptr = Kh + ((size_t)(b * LL) + p) * 256 + doff;
        const float* vptr = Vt + ((size_t)(b * LL) + p) * 256 + doff;

        const h16x2 zh = {(_Float16)0.f, (_Float16)0.f};

        auto compute = [&](h16x8 kv, f32x4 va, f32x4 vb) {
            h16x2 k2[4] = {__builtin_shufflevector(kv, kv, 0, 1),
                           __builtin_shufflevector(kv, kv, 2, 3),
                           __builtin_shufflevector(kv, kv, 4, 5),
                           __builtin_shufflevector(kv, kv, 6, 7)};
            f32x2 v2[4] = {__builtin_shufflevector(va, va, 0, 1),
                           __builtin_shufflevector(va, va, 2, 3),
                           __builtin_shufflevector(vb, vb, 0, 1),
                           __builtin_shufflevector(vb, vb, 2, 3)};
            float ps[4];
#pragma unroll
            for (int q = 0; q < 4; ++q) {
                float s = bias4;
#pragma unroll
                for (int j = 0; j < 4; ++j) {
                    h16x2 d2 = qr2[q][j] - k2[j];
                    h16x2 r2 = __builtin_elementwise_max(d2, zh);
                    s = fdot2f(w2[j], r2, s);
                }
                ps[q] = s;
            }
            const float r01 = quad_swap1(odd ? ps[0] : ps[1]);
            const float z01 = (odd ? ps[1] : ps[0]) + r01;
            const float r23 = quad_swap1(odd ? ps[2] : ps[3]);
            const float z23 = (odd ? ps[3] : ps[2]) + r23;
            const float r2f = quad_swap2(hi ? z01 : z23);
            const float zz  = (hi ? z23 : z01) + r2f;
            const float sfull = fmaxf(zz, 0.f);
            const float e = EXP2F(sfull);
            lown += e;
            const float e1 = quad_swap1(e);
            const float e2 = quad_swap2(e);
            const float e3 = quad_swap2(e1);
            const float es[4] = {e, e1, e2, e3};
#pragma unroll
            for (int s = 0; s < 4; ++s) {
                const f32x2 ee = {es[s], es[s]};
#pragma unroll
                for (int j = 0; j < 4; ++j)
                    acc2[s][j] = __builtin_elementwise_fma(v2[j], ee, acc2[s][j]);
            }
        };

        // depth-2 pipelined main loop (k rows p+16*i, i = 0..31)
        h16x8 k0 = *(const h16x8*)kptr;
        f32x4 va0 = *(const f32x4*)vptr, vb0 = *(const f32x4*)(vptr + 4);
        kptr += 16 * 256; vptr += 16 * 256;
        h16x8 k1 = *(const h16x8*)kptr;
        f32x4 va1 = *(const f32x4*)vptr, vb1 = *(const f32x4*)(vptr + 4);

#pragma unroll 1
        for (int i = 0; i < 15; ++i) {
            kptr += 16 * 256; vptr += 16 * 256;
            h16x8 k2n = *(const h16x8*)kptr;
            f32x4 va2n = *(const f32x4*)vptr, vb2n = *(const f32x4*)(vptr + 4);
            compute(k0, va0, vb0);
            kptr += 16 * 256; vptr += 16 * 256;
            h16x8 k3n = *(const h16x8*)kptr;
            f32x4 va3n = *(const f32x4*)vptr, vb3n = *(const f32x4*)(vptr + 4);
            compute(k1, va1, vb1);
            k0 = k2n; va0 = va2n; vb0 = vb2n;
            k1 = k3n; va1 = va3n; vb1 = vb3n;
        }
        compute(k0, va0, vb0);
        compute(k1, va1, vb1);

        // epilogue: dump all partials, one sync, reduce
        __syncthreads();                     // gemm-phase LDS reads long done; make union switch explicit
        {
            float* rowp = &sm.accbuf[p][lane64][0];
#pragma unroll
            for (int s = 0; s < 4; ++s)
#pragma unroll
                for (int j = 0; j < 4; ++j)
                    *(f32x2*)(rowp + s * 8 + j * 2) = acc2[s][j];
            rowp[32] = lown;
        }
        __syncthreads();

#pragma unroll
        for (int r = 0; r < 2; ++r) {
            const int o = t + 1024 * r;      // 2048 outputs / block
            const int q = o >> 8;            // 0..7 (block-local)
            const int c = o & 255;           // output feature
            const int gs = c & 7;            // group
            const int dd = c >> 3;           // within-group dim 0..31
            const int dhs = dd >> 3;         // source lane's dh
            const int rem = dd & 7;          // j*2 + parity
            const int s = dhs ^ (q & 3);     // source slot
            const int lsrc = (q >> 2) * 32 + gs * 4 + dhs;
            const int lden = (q >> 2) * 32 + gs * 4 + (q & 3);
            float sum = 0.f, den = 0.f;
#pragma unroll
            for (int pp = 0; pp < 16; ++pp) {
                sum += sm.accbuf[pp][lsrc][s * 8 + rem];
                den += sm.accbuf[pp][lden][32];
            }
            out[((size_t)(b * LL) + q0 + q) * 256 + c] = sum / den;
        }
    }
}

// ---------------------------------------------------------------------------
extern "C" void kernel_launch(void* const* d_in, const int* in_sizes, int n_in,
                              void* d_out, int out_size, void* d_ws, size_t ws_size,
                              hipStream_t stream) {
    (void)in_sizes; (void)n_in; (void)out_size; (void)ws_size;
    const float* x     = (const float*)d_in[0];
    const float* Wq    = (const float*)d_in[1];
    const float* Wk    = (const float*)d_in[2];
    const float* Wv    = (const float*)d_in[3];
    const float* w_mlp = (const float*)d_in[4];
    const float* b_mlp = (const float*)d_in[5];
    float* outp = (float*)d_out;

    _Float16* Qh = (_Float16*)d_ws;                            // 1 MB
    _Float16* Kh = (_Float16*)((char*)d_ws + (size_t)1048576); // 1 MB
    float*    Vt = (float*)((char*)d_ws + (size_t)2097152);    // 2 MB

    void* kargs[] = {
        (void*)&x, (void*)&Wq, (void*)&Wk, (void*)&Wv,
        (void*)&w_mlp, (void*)&b_mlp,
        (void*)&Qh, (void*)&Kh, (void*)&Vt, (void*)&outp
    };
    hipLaunchCooperativeKernel((const void*)fused_all, dim3(256), dim3(1024),
                               kargs, 0, stream);
}

// Round 4
// 108.363 us; speedup vs baseline: 1.5302x; 1.5302x over previous
//
#include <hip/hip_runtime.h>

typedef float f32x2 __attribute__((ext_vector_type(2)));
typedef float f32x4 __attribute__((ext_vector_type(4)));
typedef _Float16 h16x2 __attribute__((ext_vector_type(2)));
typedef _Float16 h16x4 __attribute__((ext_vector_type(4)));
typedef _Float16 h16x8 __attribute__((ext_vector_type(8)));

#define LL 512
#define M_ROWS 2048            // 4 * 512

#if __has_builtin(__builtin_amdgcn_exp2f)
#define EXP2F __builtin_amdgcn_exp2f
#else
#define EXP2F exp2f
#endif
#define LOG2E 1.44269504088896340736f

__device__ __forceinline__ float quad_swap1(float x) {
    return __int_as_float(__builtin_amdgcn_mov_dpp(__float_as_int(x), 0xB1, 0xF, 0xF, true));
}
__device__ __forceinline__ float quad_swap2(float x) {
    return __int_as_float(__builtin_amdgcn_mov_dpp(__float_as_int(x), 0x4E, 0xF, 0xF, true));
}

__device__ __forceinline__ float fdot2f(h16x2 a, h16x2 b, float c) {
#if __has_builtin(__builtin_amdgcn_fdot2)
    return __builtin_amdgcn_fdot2(a, b, c, false);
#else
    return fmaf((float)a.x, (float)b.x, fmaf((float)a.y, (float)b.y, c));
#endif
}

// ---------------------------------------------------------------------------
// Kernel 1: fp32 VALU GEMM (exact).
// LDS-BW-bound at ~10-11 us (r = 1 B/FLOP with 4x4 micro-tile) — at floor
// for this grid/occupancy tradeoff (805 MB LDS traffic / 69 TB/s = 11.6 us).
// ---------------------------------------------------------------------------
__global__ __launch_bounds__(128) void qkv_gemm(
    const float* __restrict__ X, const float* __restrict__ Wq,
    const float* __restrict__ Wk, const float* __restrict__ Wv,
    _Float16* __restrict__ Qh, _Float16* __restrict__ Kh, float* __restrict__ Vt)
{
    const int bx = blockIdx.x;           // 0..11
    const int by = blockIdx.y;           // 0..63
    const int mat = bx >> 2;
    const int n0 = (bx & 3) * 64;
    const int m0 = by * 32;
    const float* W = (mat == 0) ? Wq : (mat == 1 ? Wk : Wv);

    __shared__ float As[2][32][36];
    __shared__ float Bs[2][32][68];

    const int t = threadIdx.x;
    const int tx = t & 15;               // n micro
    const int ty = t >> 4;               // m micro (0..7)

    int am[2], ak4[2];
#pragma unroll
    for (int r = 0; r < 2; ++r) { int idx = t + 128 * r; am[r] = idx >> 3; ak4[r] = idx & 7; }
    int bn[4], bk4[4]; size_t brow[4];
#pragma unroll
    for (int r = 0; r < 4; ++r) {
        int idx = t + 128 * r; bn[r] = idx >> 3; bk4[r] = idx & 7;
        int rowc = n0 + bn[r];
        brow[r] = (mat == 2) ? (size_t)(((rowc & 31) << 3) | (rowc >> 5)) : (size_t)rowc;
    }

    f32x4 arg[2], brg[4];
    auto load_tile = [&](int kc) {
#pragma unroll
        for (int r = 0; r < 2; ++r)
            arg[r] = *(const f32x4*)(X + (size_t)(m0 + am[r]) * 256 + kc + ak4[r] * 4);
#pragma unroll
        for (int r = 0; r < 4; ++r)
            brg[r] = *(const f32x4*)(W + brow[r] * 256 + kc + bk4[r] * 4);
    };
    auto store_tile = [&](int buf) {
#pragma unroll
        for (int r = 0; r < 2; ++r)
#pragma unroll
            for (int j = 0; j < 4; ++j) As[buf][ak4[r] * 4 + j][am[r]] = arg[r][j];
#pragma unroll
        for (int r = 0; r < 4; ++r)
#pragma unroll
            for (int j = 0; j < 4; ++j) Bs[buf][bk4[r] * 4 + j][bn[r]] = brg[r][j];
    };

    load_tile(0);
    store_tile(0);
    __syncthreads();

    f32x2 c[4][2];
#pragma unroll
    for (int i = 0; i < 4; ++i) { c[i][0] = (f32x2){0.f, 0.f}; c[i][1] = (f32x2){0.f, 0.f}; }

    for (int it = 0; it < 8; ++it) {
        const int buf = it & 1;
        if (it < 7) load_tile((it + 1) * 32);
#pragma unroll
        for (int kk = 0; kk < 32; ++kk) {
            const f32x4 a4 = *(const f32x4*)&As[buf][kk][ty * 4];
            const f32x4 b4 = *(const f32x4*)&Bs[buf][kk][tx * 4];
            const f32x2 bl = __builtin_shufflevector(b4, b4, 0, 1);
            const f32x2 bh = __builtin_shufflevector(b4, b4, 2, 3);
#pragma unroll
            for (int i = 0; i < 4; ++i) {
                const f32x2 ai = {a4[i], a4[i]};
                c[i][0] += ai * bl;
                c[i][1] += ai * bh;
            }
        }
        if (it < 7) {
            __syncthreads();
            store_tile(buf ^ 1);
            __syncthreads();
        }
    }

    const int colb = n0 + tx * 4;
    if (mat == 2) {
#pragma unroll
        for (int i = 0; i < 4; ++i) {
            f32x4 v = {c[i][0].x, c[i][0].y, c[i][1].x, c[i][1].y};
            *(f32x4*)(Vt + (size_t)(m0 + ty * 4 + i) * 256 + colb) = v;
        }
    } else {
        _Float16* Hb = (mat == 0) ? Qh : Kh;
#pragma unroll
        for (int i = 0; i < 4; ++i) {
            h16x4 hv = {(_Float16)c[i][0].x, (_Float16)c[i][0].y,
                        (_Float16)c[i][1].x, (_Float16)c[i][1].y};
            *(h16x4*)(Hb + (size_t)(m0 + ty * 4 + i) * 256 + colb) = hv;
        }
    }
}

// ---------------------------------------------------------------------------
// Kernel 2: fused grouped-MLP attention — f16 score, exp-deduped quad
// transpose-reduce, epilogue split into 2 rounds of 2 q:
// LDS 38,912 B -> 4 blocks/CU (8 waves/SIMD) for chain-stall coverage.
// grid 512 = 4 batches x 128 q-tiles (4 q rows), 512 threads.
// Measured ~12 us ≈ 85% of the 10.2 us VALU-issue floor (score kernel is
// irreducibly 3 ops / 2 dims for w·relu(q-k); R12 dedup + R13 pipeline both
// null -> not BW/latency-bound).
// ---------------------------------------------------------------------------
__global__ __launch_bounds__(512, 4) void attn_fused(
    const _Float16* __restrict__ Qh, const _Float16* __restrict__ Kh,
    const float* __restrict__ Vt,
    const float* __restrict__ w_mlp, const float* __restrict__ b_mlp,
    float* __restrict__ out)
{
    const int bid = blockIdx.x;
    const int b = bid & 3;
    const int q0 = (bid >> 2) * 4;

    const int t = threadIdx.x;
    const int dh = t & 3;
    const int p = t >> 5;                    // 0..15
    const int lane32 = t & 31;               // g*4 + dh
    const int g = lane32 >> 2;

    __shared__ float accbuf[16][32][19];     // 38,912 B (2q x 8 + l[2] + pad)

    const int doff = g * 32 + dh * 8;
    const float bias4 = b_mlp[0] * (LOG2E * 0.25f);
    const bool odd = (dh & 1) != 0;
    const bool hi  = (dh & 2) != 0;

    h16x2 w2[4];
    {
        f32x4 wa = *(const f32x4*)(w_mlp + dh * 8);
        f32x4 wb = *(const f32x4*)(w_mlp + dh * 8 + 4);
        wa *= LOG2E; wb *= LOG2E;
        w2[0] = (h16x2){(_Float16)wa.x, (_Float16)wa.y};
        w2[1] = (h16x2){(_Float16)wa.z, (_Float16)wa.w};
        w2[2] = (h16x2){(_Float16)wb.x, (_Float16)wb.y};
        w2[3] = (h16x2){(_Float16)wb.z, (_Float16)wb.w};
    }

    h16x2 qr2[4][4];
#pragma unroll
    for (int q = 0; q < 4; ++q) {
        const h16x8 qv = *(const h16x8*)(Qh + ((size_t)(b * LL) + q0 + q) * 256 + doff);
        qr2[q][0] = __builtin_shufflevector(qv, qv, 0, 1);
        qr2[q][1] = __builtin_shufflevector(qv, qv, 2, 3);
        qr2[q][2] = __builtin_shufflevector(qv, qv, 4, 5);
        qr2[q][3] = __builtin_shufflevector(qv, qv, 6, 7);
    }

    f32x2 acc2[4][4];                        // slot s <-> q = dh ^ s
#pragma unroll
    for (int s = 0; s < 4; ++s)
#pragma unroll
        for (int j = 0; j < 4; ++j) acc2[s][j] = (f32x2){0.f, 0.f};
    float lown = 0.f;                        // l for q == dh

    const _Float16* kptr = Kh + ((size_t)(b * LL) + p) * 256 + doff;
    const float* vptr = Vt + ((size_t)(b * LL) + p) * 256 + doff;

    const h16x2 zh = {(_Float16)0.f, (_Float16)0.f};

    auto compute = [&](h16x8 kv, f32x4 va, f32x4 vb) {
        h16x2 k2[4] = {__builtin_shufflevector(kv, kv, 0, 1),
                       __builtin_shufflevector(kv, kv, 2, 3),
                       __builtin_shufflevector(kv, kv, 4, 5),
                       __builtin_shufflevector(kv, kv, 6, 7)};
        f32x2 v2[4] = {__builtin_shufflevector(va, va, 0, 1),
                       __builtin_shufflevector(va, va, 2, 3),
                       __builtin_shufflevector(vb, vb, 0, 1),
                       __builtin_shufflevector(vb, vb, 2, 3)};
        float ps[4];
#pragma unroll
        for (int q = 0; q < 4; ++q) {
            float s = bias4;
#pragma unroll
            for (int j = 0; j < 4; ++j) {
                h16x2 d2 = qr2[q][j] - k2[j];
                h16x2 r2 = __builtin_elementwise_max(d2, zh);
                s = fdot2f(w2[j], r2, s);
            }
            ps[q] = s;
        }
        // quad transpose-reduce: lane dh ends with full sum for q == dh
        const float r01 = quad_swap1(odd ? ps[0] : ps[1]);
        const float z01 = (odd ? ps[1] : ps[0]) + r01;
        const float r23 = quad_swap1(odd ? ps[2] : ps[3]);
        const float z23 = (odd ? ps[3] : ps[2]) + r23;
        const float r2f = quad_swap2(hi ? z01 : z23);
        const float zz  = (hi ? z23 : z01) + r2f;
        const float sfull = fmaxf(zz, 0.f);
        const float e = EXP2F(sfull);        // one exp per (quad, q)
        lown += e;
        const float e1 = quad_swap1(e);
        const float e2 = quad_swap2(e);
        const float e3 = quad_swap2(e1);
        const float es[4] = {e, e1, e2, e3};
#pragma unroll
        for (int s = 0; s < 4; ++s) {
            const f32x2 ee = {es[s], es[s]};
#pragma unroll
            for (int j = 0; j < 4; ++j)
                acc2[s][j] = __builtin_elementwise_fma(v2[j], ee, acc2[s][j]);
        }
    };

    h16x8 kc = *(const h16x8*)kptr;
    f32x4 va = *(const f32x4*)vptr, vb = *(const f32x4*)(vptr + 4);
#pragma unroll 1
    for (int i = 0; i < 31; ++i) {
        kptr += 16 * 256; vptr += 16 * 256;
        h16x8 kn = *(const h16x8*)kptr;
        f32x4 va2 = *(const f32x4*)vptr, vb2 = *(const f32x4*)(vptr + 4);
        compute(kc, va, vb);
        kc = kn; va = va2; vb = vb2;
    }
    compute(kc, va, vb);

    // ---- epilogue: 2 rounds of 2 q; lane's slot s holds q = dh ^ s ----
    const int c_o = t & 255;
    const int g_o = c_o & 7, d_o = c_o >> 3;
    const int rowb = g_o * 4 + (d_o >> 3);
    const int colb = d_o & 7;
    const int qh2 = t >> 8;                  // 0..1

#pragma unroll
    for (int r = 0; r < 2; ++r) {
        if (r) __syncthreads();              // previous round's reads done
        {
            float* rowp = &accbuf[p][lane32][0];
#pragma unroll
            for (int s = 0; s < 4; ++s) {
                const int qq = dh ^ s;
                if ((qq >> 1) == r) {
#pragma unroll
                    for (int j = 0; j < 4; ++j)
                        *(f32x2*)(rowp + (qq & 1) * 8 + j * 2) = acc2[s][j];
                }
            }
            if ((dh >> 1) == r) rowp[16 + (dh & 1)] = lown;
        }
        __syncthreads();
        {
            const int q = 2 * r + qh2;
            float s = 0.f, ls = 0.f;
#pragma unroll
            for (int pp = 0; pp < 16; ++pp) {
                s  += accbuf[pp][rowb][qh2 * 8 + colb];
                ls += accbuf[pp][g_o * 4 + q][16 + qh2];
            }
            out[((size_t)(b * LL) + q0 + q) * 256 + c_o] = s / ls;
        }
    }
}

// ---------------------------------------------------------------------------
extern "C" void kernel_launch(void* const* d_in, const int* in_sizes, int n_in,
                              void* d_out, int out_size, void* d_ws, size_t ws_size,
                              hipStream_t stream) {
    (void)in_sizes; (void)n_in; (void)out_size; (void)ws_size;
    const float* x     = (const float*)d_in[0];
    const float* Wq    = (const float*)d_in[1];
    const float* Wk    = (const float*)d_in[2];
    const float* Wv    = (const float*)d_in[3];
    const float* w_mlp = (const float*)d_in[4];
    const float* b_mlp = (const float*)d_in[5];
    float* outp = (float*)d_out;

    _Float16* Qh = (_Float16*)d_ws;                            // 1 MB
    _Float16* Kh = (_Float16*)((char*)d_ws + (size_t)1048576); // 1 MB
    float*    Vt = (float*)((char*)d_ws + (size_t)2097152);    // 2 MB

    qkv_gemm<<<dim3(12, 64), 128, 0, stream>>>(x, Wq, Wk, Wv, Qh, Kh, Vt);
    attn_fused<<<dim3(512), 512, 0, stream>>>(Qh, Kh, Vt, w_mlp, b_mlp, outp);
}